// Round 5
// baseline (1230.396 us; speedup 1.0000x reference)
//
#include <hip/hip_runtime.h>
#include <stdint.h>

// ---------------------------------------------------------------------------
// MLP_Model: candidates head + per-route Customer MLP + 2-layer GRU + FC head
// R5: gru_lp — LAYER-PARALLEL software-pipelined GRU.
//   1024 threads = 16 waves; wave (layer = w>>3, J = w&7).
//   Phase p: layer-0 waves compute step p, layer-1 waves compute step p-1.
//   ONE barrier per phase (25 phases) vs R4's 48.
//   Layer-0 wave: wih0+wh0 resident (60 VGPR). Layer-1 wave: whh1 resident
//   (48 VGPR), wih1 streamed from L2. 4 waves/SIMD at __launch_bounds__(1024,4).
// pack/mlp/final unchanged.
// ws layout: [0,344064) packed bf16 weights; [344064,38092800) x2 bf16;
// [38092800,...) h1 final fp32 (~50.7 MB total).
// ---------------------------------------------------------------------------

#define NSEQ   24576   // 512 * 48
#define TSTEPS 24

typedef __attribute__((ext_vector_type(8))) short bf16x8;
typedef __attribute__((ext_vector_type(4))) float floatx4;

// packed-weight element offsets (uint16 units)
#define PK_W1    0
#define PK_W2    8192
#define PK_WIH0  12288
#define PK_WHH0  24576
#define PK_WIH1  73728
#define PK_WHH1  122880
#define PK_END   172032
#define X2_EL    172032                 // x2: [t][seq][32] bf16
#define HOUT_BYTE 38092800              // h1 final: [seq][128] fp32

#define MFMA(a,b,c) c = __builtin_amdgcn_mfma_f32_16x16x32_bf16(a, b, c, 0, 0, 0)

__device__ __forceinline__ uint16_t f2bf(float f) {
  uint32_t u = __float_as_uint(f);
  u += 0x7FFFu + ((u >> 16) & 1u);           // RNE
  return (uint16_t)(u >> 16);
}
__device__ __forceinline__ float fast_sigmoid(float x) {
  float e = __builtin_amdgcn_exp2f(-1.4426950408889634f * x);
  return __builtin_amdgcn_rcpf(1.0f + e);
}
__device__ __forceinline__ float fast_tanh(float x) {
  float e = __builtin_amdgcn_exp2f(-2.8853900817779268f * x);
  return 2.0f * __builtin_amdgcn_rcpf(1.0f + e) - 1.0f;
}
__device__ __forceinline__ bf16x8 ldf(const uint16_t* p) {
  return *(const bf16x8*)p;
}

// ---------------------------------------------------------------------------
// Kernel 0: pack all weights to bf16 B-fragment layout. (unchanged)
// ---------------------------------------------------------------------------
__global__ __launch_bounds__(256) void pack_weights(
    const float* __restrict__ w1, const float* __restrict__ w2,
    const float* __restrict__ wih0, const float* __restrict__ whh0,
    const float* __restrict__ wih1, const float* __restrict__ whh1,
    uint16_t* __restrict__ ws) {
  int idx = blockIdx.x * 256 + threadIdx.x;
  if (idx >= PK_END) return;
  const float* W; int N, KB, Kreal, base;
  if      (idx <  8192) { W = w1;   N = 128; KB = 2; Kreal = 36;  base = 0; }
  else if (idx < 12288) { W = w2;   N = 32;  KB = 4; Kreal = 128; base = 8192; }
  else if (idx < 24576) { W = wih0; N = 384; KB = 1; Kreal = 32;  base = 12288; }
  else if (idx < 73728) { W = whh0; N = 384; KB = 4; Kreal = 128; base = 24576; }
  else if (idx < 122880){ W = wih1; N = 384; KB = 4; Kreal = 128; base = 73728; }
  else                  { W = whh1; N = 384; KB = 4; Kreal = 128; base = 122880; }
  int li = idx - base;
  int frag = li >> 9;
  int e = li & 511;
  int lane = e >> 3, j = e & 7;
  int kb = frag % KB, nt = frag / KB;
  int k = kb * 32 + (lane >> 4) * 8 + j;
  int n = nt * 16 + (lane & 15);
  float v = (k < Kreal) ? W[k * N + n] : 0.0f;
  ws[base + li] = f2bf(v);
}

// ---------------------------------------------------------------------------
// Kernel 1: Customer MLP (unchanged from R1)
// ---------------------------------------------------------------------------
__global__ __launch_bounds__(256) void mlp_kernel(
    const float* __restrict__ customers, const float* __restrict__ b1,
    const float* __restrict__ b2, const uint16_t* __restrict__ wpk,
    uint16_t* __restrict__ x2out) {
  __shared__ uint16_t sA[128 * 136];
  const int r0 = blockIdx.x * 128;
  const int t  = r0 / NSEQ;
  const int s0 = r0 % NSEQ;
  const int tid = threadIdx.x;
  const int w = tid >> 6, l = tid & 63, q = l >> 4, c = l & 15;
  const int lo8 = l * 8;

  float b1r[8], b2r[2];
  #pragma unroll
  for (int nt = 0; nt < 8; ++nt) b1r[nt] = b1[nt * 16 + c];
  b2r[0] = b2[c]; b2r[1] = b2[16 + c];

  floatx4 acc[2][8];
  #pragma unroll
  for (int mi = 0; mi < 2; ++mi)
    #pragma unroll
    for (int nt = 0; nt < 8; ++nt) acc[mi][nt] = (floatx4){0.f, 0.f, 0.f, 0.f};

  #pragma unroll
  for (int mi = 0; mi < 2; ++mi) {
    const int mt = 2 * w + mi;
    const int seq = s0 + mt * 16 + c;
    const float* xp = customers + (size_t)seq * 864 + t * 36;
    floatx4 u0 = *(const floatx4*)(xp + q * 8);
    floatx4 u1 = *(const floatx4*)(xp + q * 8 + 4);
    bf16x8 a0;
    a0[0] = (short)f2bf(u0[0]); a0[1] = (short)f2bf(u0[1]);
    a0[2] = (short)f2bf(u0[2]); a0[3] = (short)f2bf(u0[3]);
    a0[4] = (short)f2bf(u1[0]); a0[5] = (short)f2bf(u1[1]);
    a0[6] = (short)f2bf(u1[2]); a0[7] = (short)f2bf(u1[3]);
    bf16x8 a1x = (bf16x8){0,0,0,0,0,0,0,0};
    if (q == 0) {
      floatx4 u2 = *(const floatx4*)(xp + 32);
      a1x[0] = (short)f2bf(u2[0]); a1x[1] = (short)f2bf(u2[1]);
      a1x[2] = (short)f2bf(u2[2]); a1x[3] = (short)f2bf(u2[3]);
    }
    #pragma unroll
    for (int nt = 0; nt < 8; ++nt) {
      bf16x8 bv0 = ldf(wpk + PK_W1 + (nt * 2 + 0) * 512 + lo8);
      bf16x8 bv1 = ldf(wpk + PK_W1 + (nt * 2 + 1) * 512 + lo8);
      MFMA(a0,  bv0, acc[mi][nt]);
      MFMA(a1x, bv1, acc[mi][nt]);
    }
  }
  #pragma unroll
  for (int mi = 0; mi < 2; ++mi) {
    const int mt = 2 * w + mi;
    #pragma unroll
    for (int nt = 0; nt < 8; ++nt)
      #pragma unroll
      for (int e = 0; e < 4; ++e) {
        float v = fast_tanh(acc[mi][nt][e] + b1r[nt]);
        sA[(mt * 16 + q * 4 + e) * 136 + nt * 16 + c] = f2bf(v);
      }
  }
  __syncthreads();

  floatx4 acc2[2][2];
  #pragma unroll
  for (int mi = 0; mi < 2; ++mi)
    #pragma unroll
    for (int nt = 0; nt < 2; ++nt) acc2[mi][nt] = (floatx4){0.f, 0.f, 0.f, 0.f};

  #pragma unroll
  for (int kb = 0; kb < 4; ++kb) {
    bf16x8 av0 = ldf(&sA[((2 * w + 0) * 16 + c) * 136 + kb * 32 + q * 8]);
    bf16x8 av1 = ldf(&sA[((2 * w + 1) * 16 + c) * 136 + kb * 32 + q * 8]);
    #pragma unroll
    for (int nt = 0; nt < 2; ++nt) {
      bf16x8 bv = ldf(wpk + PK_W2 + (nt * 4 + kb) * 512 + lo8);
      MFMA(av0, bv, acc2[0][nt]);
      MFMA(av1, bv, acc2[1][nt]);
    }
  }
  #pragma unroll
  for (int mi = 0; mi < 2; ++mi) {
    const int mt = 2 * w + mi;
    #pragma unroll
    for (int nt = 0; nt < 2; ++nt)
      #pragma unroll
      for (int e = 0; e < 4; ++e) {
        float v = fast_tanh(acc2[mi][nt][e] + b2r[nt]);
        int m = mt * 16 + q * 4 + e;
        x2out[(size_t)(r0 + m) * 32 + nt * 16 + c] = f2bf(v);
      }
  }
}

// ---------------------------------------------------------------------------
// Kernel 2 (R5): layer-parallel pipelined GRU. 1024 thr = 16 waves.
// wave (layer = w>>3, J = w&7); 32 seqs/block; grid 768; 1 barrier/phase.
// Buffers: phase p: layer0 reads hl0[p^1&1], writes hl0[p&1];
//          layer1 reads hl0[(p+1)&1] (=h0(p-1)), hl1[p&1] (=h1(p-2)),
//          writes hl1[(p+1)&1] (=h1(p-1)).
// ---------------------------------------------------------------------------
__global__ __launch_bounds__(1024, 4) void gru_lp(
    const uint16_t* __restrict__ wpk, const uint16_t* __restrict__ x2,
    const float* __restrict__ bih0, const float* __restrict__ bhh0,
    const float* __restrict__ bih1, const float* __restrict__ bhh1,
    float* __restrict__ hout) {
  __shared__ uint16_t hl0[2][32 * 136];
  __shared__ uint16_t hl1[2][32 * 136];
  const int seq0 = blockIdx.x * 32;
  const int tid = threadIdx.x;
  const int wv = tid >> 6, l = tid & 63, q = l >> 4, c = l & 15;
  const int layer = wv >> 3, J = wv & 7;
  const int lo8 = l * 8;

  { uint32_t* z0 = (uint32_t*)hl0;
    for (int i = tid; i < 2 * 32 * 68; i += 1024) z0[i] = 0u;
    uint32_t* z1 = (uint32_t*)hl1;
    for (int i = tid; i < 2 * 32 * 68; i += 1024) z1[i] = 0u; }

  floatx4 hm[2];
  hm[0] = (floatx4){0.f, 0.f, 0.f, 0.f};
  hm[1] = (floatx4){0.f, 0.f, 0.f, 0.f};

  const int col = J * 16 + c;
  float bR, bZ, bN, bH;
  // layer-0 resident weights
  bf16x8 wi0[3], wh0[3][4];
  // layer-1 resident weights (whh1 only; wih1 streamed)
  bf16x8 wh1[3][4];
  bf16x8 axc0, axc1;

  if (layer == 0) {
    #pragma unroll
    for (int g = 0; g < 3; ++g) {
      wi0[g] = ldf(wpk + PK_WIH0 + (g * 8 + J) * 512 + lo8);
      #pragma unroll
      for (int kb = 0; kb < 4; ++kb)
        wh0[g][kb] = ldf(wpk + PK_WHH0 + ((g * 8 + J) * 4 + kb) * 512 + lo8);
    }
    bR = bih0[col]       + bhh0[col];
    bZ = bih0[128 + col] + bhh0[128 + col];
    bN = bih0[256 + col];
    bH = bhh0[256 + col];
    axc0 = ldf(x2 + (size_t)(seq0 + c) * 32 + q * 8);
    axc1 = ldf(x2 + (size_t)(seq0 + 16 + c) * 32 + q * 8);
  } else {
    #pragma unroll
    for (int g = 0; g < 3; ++g)
      #pragma unroll
      for (int kb = 0; kb < 4; ++kb)
        wh1[g][kb] = ldf(wpk + PK_WHH1 + ((g * 8 + J) * 4 + kb) * 512 + lo8);
    bR = bih1[col]       + bhh1[col];
    bZ = bih1[128 + col] + bhh1[128 + col];
    bN = bih1[256 + col];
    bH = bhh1[256 + col];
  }
  __syncthreads();

  #pragma unroll 1
  for (int p = 0; p <= TSTEPS; ++p) {
    const int cw = p & 1, pv = cw ^ 1;
    if (layer == 0) {
      if (p < TSTEPS) {
        const int tn = (p < TSTEPS - 1) ? p + 1 : p;
        bf16x8 axn0 = ldf(x2 + ((size_t)tn * NSEQ + seq0 + c) * 32 + q * 8);
        bf16x8 axn1 = ldf(x2 + ((size_t)tn * NSEQ + seq0 + 16 + c) * 32 + q * 8);
        floatx4 aR[2], aZ[2], aN[2], aH[2];
        #pragma unroll
        for (int mi = 0; mi < 2; ++mi) {
          aR[mi] = (floatx4){bR, bR, bR, bR};
          aZ[mi] = (floatx4){bZ, bZ, bZ, bZ};
          aN[mi] = (floatx4){bN, bN, bN, bN};
          aH[mi] = (floatx4){bH, bH, bH, bH};
        }
        #pragma unroll
        for (int kb = 0; kb < 4; ++kb) {
          bf16x8 a0 = ldf(&hl0[pv][(c)      * 136 + kb * 32 + q * 8]);
          bf16x8 a1 = ldf(&hl0[pv][(16 + c) * 136 + kb * 32 + q * 8]);
          MFMA(a0, wh0[0][kb], aR[0]); MFMA(a1, wh0[0][kb], aR[1]);
          MFMA(a0, wh0[1][kb], aZ[0]); MFMA(a1, wh0[1][kb], aZ[1]);
          MFMA(a0, wh0[2][kb], aH[0]); MFMA(a1, wh0[2][kb], aH[1]);
        }
        MFMA(axc0, wi0[0], aR[0]); MFMA(axc1, wi0[0], aR[1]);
        MFMA(axc0, wi0[1], aZ[0]); MFMA(axc1, wi0[1], aZ[1]);
        MFMA(axc0, wi0[2], aN[0]); MFMA(axc1, wi0[2], aN[1]);
        #pragma unroll
        for (int mi = 0; mi < 2; ++mi)
          #pragma unroll
          for (int e = 0; e < 4; ++e) {
            float r  = fast_sigmoid(aR[mi][e]);
            float zz = fast_sigmoid(aZ[mi][e]);
            float nn = fast_tanh(aN[mi][e] + r * aH[mi][e]);
            float hv = nn + zz * (hm[mi][e] - nn);
            hm[mi][e] = hv;
            hl0[cw][(mi * 16 + q * 4 + e) * 136 + J * 16 + c] = f2bf(hv);
          }
        axc0 = axn0; axc1 = axn1;
      }
    } else {
      if (p > 0) {
        floatx4 aR[2], aZ[2], aN[2], aH[2];
        #pragma unroll
        for (int mi = 0; mi < 2; ++mi) {
          aR[mi] = (floatx4){bR, bR, bR, bR};
          aZ[mi] = (floatx4){bZ, bZ, bZ, bZ};
          aN[mi] = (floatx4){bN, bN, bN, bN};
          aH[mi] = (floatx4){bH, bH, bH, bH};
        }
        #pragma unroll
        for (int kb = 0; kb < 4; ++kb) {
          bf16x8 ai0 = ldf(&hl0[pv][(c)      * 136 + kb * 32 + q * 8]);
          bf16x8 ai1 = ldf(&hl0[pv][(16 + c) * 136 + kb * 32 + q * 8]);
          bf16x8 ah0 = ldf(&hl1[cw][(c)      * 136 + kb * 32 + q * 8]);
          bf16x8 ah1 = ldf(&hl1[cw][(16 + c) * 136 + kb * 32 + q * 8]);
          bf16x8 w_r = ldf(wpk + PK_WIH1 + ((0 * 8 + J) * 4 + kb) * 512 + lo8);
          bf16x8 w_z = ldf(wpk + PK_WIH1 + ((1 * 8 + J) * 4 + kb) * 512 + lo8);
          bf16x8 w_n = ldf(wpk + PK_WIH1 + ((2 * 8 + J) * 4 + kb) * 512 + lo8);
          MFMA(ai0, w_r, aR[0]); MFMA(ai1, w_r, aR[1]);
          MFMA(ai0, w_z, aZ[0]); MFMA(ai1, w_z, aZ[1]);
          MFMA(ai0, w_n, aN[0]); MFMA(ai1, w_n, aN[1]);
          MFMA(ah0, wh1[0][kb], aR[0]); MFMA(ah1, wh1[0][kb], aR[1]);
          MFMA(ah0, wh1[1][kb], aZ[0]); MFMA(ah1, wh1[1][kb], aZ[1]);
          MFMA(ah0, wh1[2][kb], aH[0]); MFMA(ah1, wh1[2][kb], aH[1]);
        }
        #pragma unroll
        for (int mi = 0; mi < 2; ++mi)
          #pragma unroll
          for (int e = 0; e < 4; ++e) {
            float r  = fast_sigmoid(aR[mi][e]);
            float zz = fast_sigmoid(aZ[mi][e]);
            float nn = fast_tanh(aN[mi][e] + r * aH[mi][e]);
            float hv = nn + zz * (hm[mi][e] - nn);
            hm[mi][e] = hv;
            hl1[pv][(mi * 16 + q * 4 + e) * 136 + J * 16 + c] = f2bf(hv);
          }
      }
    }
    __syncthreads();
  }

  if (layer == 1) {
    #pragma unroll
    for (int mi = 0; mi < 2; ++mi)
      #pragma unroll
      for (int e = 0; e < 4; ++e) {
        int seq = seq0 + mi * 16 + q * 4 + e;
        hout[(size_t)seq * 128 + J * 16 + c] = hm[mi][e];
      }
  }
}

// ---------------------------------------------------------------------------
// Kernel 3: mean over routes + candidate head + fc1/fc2/fc3 (unchanged)
// ---------------------------------------------------------------------------
__global__ __launch_bounds__(192) void final_kernel(
    const float* __restrict__ hout, const float* __restrict__ cands,
    const float* __restrict__ cw, const float* __restrict__ cb,
    const float* __restrict__ f1w, const float* __restrict__ f1b,
    const float* __restrict__ f2w, const float* __restrict__ f2b,
    const float* __restrict__ f3w, const float* __restrict__ f3b,
    float* __restrict__ out) {
  __shared__ float hc[192];
  __shared__ float v1[128];
  __shared__ float v2[128];
  __shared__ float red[128];
  const int b = blockIdx.x, tid = threadIdx.x;
  if (tid < 128) {
    float s = 0.f;
    const float* hp = hout + (size_t)(b * 48) * 128 + tid;
    #pragma unroll 4
    for (int r = 0; r < 48; ++r) s += hp[r * 128];
    hc[tid] = s * (1.0f / 48.0f);
  } else {
    int j = tid - 128;
    float s = cb[j];
    const float* cp = cands + b * 72;
    #pragma unroll 8
    for (int k = 0; k < 72; ++k) s += cp[k] * cw[k * 64 + j];
    hc[128 + j] = s;
  }
  __syncthreads();
  if (tid < 128) {
    float s = f1b[tid];
    for (int k = 0; k < 192; ++k) s += hc[k] * f1w[k * 128 + tid];
    v1[tid] = fast_tanh(s);
  }
  __syncthreads();
  if (tid < 128) {
    float s = f2b[tid];
    for (int k = 0; k < 128; ++k) s += v1[k] * f2w[k * 128 + tid];
    v2[tid] = fast_tanh(s);
  }
  __syncthreads();
  if (tid < 128) red[tid] = v2[tid] * f3w[tid];
  __syncthreads();
  if (tid < 64) {
    float s = red[tid] + red[tid + 64];
    s += __shfl_down(s, 32);
    s += __shfl_down(s, 16);
    s += __shfl_down(s, 8);
    s += __shfl_down(s, 4);
    s += __shfl_down(s, 2);
    s += __shfl_down(s, 1);
    if (tid == 0) out[b] = s + f3b[0];
  }
}

// ---------------------------------------------------------------------------
extern "C" void kernel_launch(void* const* d_in, const int* in_sizes, int n_in,
                              void* d_out, int out_size, void* d_ws, size_t ws_size,
                              hipStream_t stream) {
  const float* cand  = (const float*)d_in[0];
  const float* cust  = (const float*)d_in[1];
  const float* w1    = (const float*)d_in[2];
  const float* b1    = (const float*)d_in[3];
  const float* w2    = (const float*)d_in[4];
  const float* b2    = (const float*)d_in[5];
  const float* wih0  = (const float*)d_in[6];
  const float* whh0  = (const float*)d_in[7];
  const float* bih0  = (const float*)d_in[8];
  const float* bhh0  = (const float*)d_in[9];
  const float* wih1  = (const float*)d_in[10];
  const float* whh1  = (const float*)d_in[11];
  const float* bih1  = (const float*)d_in[12];
  const float* bhh1  = (const float*)d_in[13];
  const float* cw    = (const float*)d_in[14];
  const float* cb    = (const float*)d_in[15];
  const float* f1w   = (const float*)d_in[16];
  const float* f1b   = (const float*)d_in[17];
  const float* f2w   = (const float*)d_in[18];
  const float* f2b   = (const float*)d_in[19];
  const float* f3w   = (const float*)d_in[20];
  const float* f3b   = (const float*)d_in[21];

  uint16_t* wsp = (uint16_t*)d_ws;
  uint16_t* x2p = wsp + X2_EL;
  float* hout = (float*)((char*)d_ws + HOUT_BYTE);
  float* outp = (float*)d_out;

  pack_weights<<<(PK_END + 255) / 256, 256, 0, stream>>>(w1, w2, wih0, whh0, wih1, whh1, wsp);
  mlp_kernel<<<(NSEQ * TSTEPS) / 128, 256, 0, stream>>>(cust, b1, b2, wsp, x2p);
  gru_lp<<<NSEQ / 32, 1024, 0, stream>>>(wsp, x2p, bih0, bhh0, bih1, bhh1, hout);
  final_kernel<<<512, 192, 0, stream>>>(hout, cand, cw, cb, f1w, f1b, f2w, f2b, f3w, f3b, outp);
}

// Round 6
// 465.761 us; speedup vs baseline: 2.6417x; 2.6417x over previous
//
#include <hip/hip_runtime.h>
#include <stdint.h>

// ---------------------------------------------------------------------------
// MLP_Model: candidates head + per-route Customer MLP + 2-layer GRU + FC head
// R6: gru_mg — R4 structure (512 thr = 8 waves, wave owns J-tile, weights
// register-resident, 2 waves/SIMD) with L1(t) and L0(t+1) MERGED into ONE
// barrier interval: 25 barriers instead of 48. L1 gates complete before L0
// gates start (keeps peak pressure at R4's ~250 regs, no spills).
// R5's 1024-thr layer-parallel variant spilled to scratch (VGPR=64, 3GB
// FETCH) — 1024-thr blocks cap regs at 128/wave; do not repeat.
// ws layout: [0,344064) packed bf16 weights; [344064,38092800) x2 bf16;
// [38092800,...) h1 final fp32 (~50.7 MB total).
// ---------------------------------------------------------------------------

#define NSEQ   24576   // 512 * 48
#define TSTEPS 24

typedef __attribute__((ext_vector_type(8))) short bf16x8;
typedef __attribute__((ext_vector_type(4))) float floatx4;

// packed-weight element offsets (uint16 units)
#define PK_W1    0
#define PK_W2    8192
#define PK_WIH0  12288
#define PK_WHH0  24576
#define PK_WIH1  73728
#define PK_WHH1  122880
#define PK_END   172032
#define X2_EL    172032                 // x2: [t][seq][32] bf16
#define HOUT_BYTE 38092800              // h1 final: [seq][128] fp32

#define MFMA(a,b,c) c = __builtin_amdgcn_mfma_f32_16x16x32_bf16(a, b, c, 0, 0, 0)

__device__ __forceinline__ uint16_t f2bf(float f) {
  uint32_t u = __float_as_uint(f);
  u += 0x7FFFu + ((u >> 16) & 1u);           // RNE
  return (uint16_t)(u >> 16);
}
__device__ __forceinline__ float fast_sigmoid(float x) {
  float e = __builtin_amdgcn_exp2f(-1.4426950408889634f * x);
  return __builtin_amdgcn_rcpf(1.0f + e);
}
__device__ __forceinline__ float fast_tanh(float x) {
  float e = __builtin_amdgcn_exp2f(-2.8853900817779268f * x);
  return 2.0f * __builtin_amdgcn_rcpf(1.0f + e) - 1.0f;
}
__device__ __forceinline__ bf16x8 ldf(const uint16_t* p) {
  return *(const bf16x8*)p;
}

// ---------------------------------------------------------------------------
// Kernel 0: pack all weights to bf16 B-fragment layout. (unchanged)
// ---------------------------------------------------------------------------
__global__ __launch_bounds__(256) void pack_weights(
    const float* __restrict__ w1, const float* __restrict__ w2,
    const float* __restrict__ wih0, const float* __restrict__ whh0,
    const float* __restrict__ wih1, const float* __restrict__ whh1,
    uint16_t* __restrict__ ws) {
  int idx = blockIdx.x * 256 + threadIdx.x;
  if (idx >= PK_END) return;
  const float* W; int N, KB, Kreal, base;
  if      (idx <  8192) { W = w1;   N = 128; KB = 2; Kreal = 36;  base = 0; }
  else if (idx < 12288) { W = w2;   N = 32;  KB = 4; Kreal = 128; base = 8192; }
  else if (idx < 24576) { W = wih0; N = 384; KB = 1; Kreal = 32;  base = 12288; }
  else if (idx < 73728) { W = whh0; N = 384; KB = 4; Kreal = 128; base = 24576; }
  else if (idx < 122880){ W = wih1; N = 384; KB = 4; Kreal = 128; base = 73728; }
  else                  { W = whh1; N = 384; KB = 4; Kreal = 128; base = 122880; }
  int li = idx - base;
  int frag = li >> 9;
  int e = li & 511;
  int lane = e >> 3, j = e & 7;
  int kb = frag % KB, nt = frag / KB;
  int k = kb * 32 + (lane >> 4) * 8 + j;
  int n = nt * 16 + (lane & 15);
  float v = (k < Kreal) ? W[k * N + n] : 0.0f;
  ws[base + li] = f2bf(v);
}

// ---------------------------------------------------------------------------
// Kernel 1: Customer MLP (unchanged from R1)
// ---------------------------------------------------------------------------
__global__ __launch_bounds__(256) void mlp_kernel(
    const float* __restrict__ customers, const float* __restrict__ b1,
    const float* __restrict__ b2, const uint16_t* __restrict__ wpk,
    uint16_t* __restrict__ x2out) {
  __shared__ uint16_t sA[128 * 136];
  const int r0 = blockIdx.x * 128;
  const int t  = r0 / NSEQ;
  const int s0 = r0 % NSEQ;
  const int tid = threadIdx.x;
  const int w = tid >> 6, l = tid & 63, q = l >> 4, c = l & 15;
  const int lo8 = l * 8;

  float b1r[8], b2r[2];
  #pragma unroll
  for (int nt = 0; nt < 8; ++nt) b1r[nt] = b1[nt * 16 + c];
  b2r[0] = b2[c]; b2r[1] = b2[16 + c];

  floatx4 acc[2][8];
  #pragma unroll
  for (int mi = 0; mi < 2; ++mi)
    #pragma unroll
    for (int nt = 0; nt < 8; ++nt) acc[mi][nt] = (floatx4){0.f, 0.f, 0.f, 0.f};

  #pragma unroll
  for (int mi = 0; mi < 2; ++mi) {
    const int mt = 2 * w + mi;
    const int seq = s0 + mt * 16 + c;
    const float* xp = customers + (size_t)seq * 864 + t * 36;
    floatx4 u0 = *(const floatx4*)(xp + q * 8);
    floatx4 u1 = *(const floatx4*)(xp + q * 8 + 4);
    bf16x8 a0;
    a0[0] = (short)f2bf(u0[0]); a0[1] = (short)f2bf(u0[1]);
    a0[2] = (short)f2bf(u0[2]); a0[3] = (short)f2bf(u0[3]);
    a0[4] = (short)f2bf(u1[0]); a0[5] = (short)f2bf(u1[1]);
    a0[6] = (short)f2bf(u1[2]); a0[7] = (short)f2bf(u1[3]);
    bf16x8 a1x = (bf16x8){0,0,0,0,0,0,0,0};
    if (q == 0) {
      floatx4 u2 = *(const floatx4*)(xp + 32);
      a1x[0] = (short)f2bf(u2[0]); a1x[1] = (short)f2bf(u2[1]);
      a1x[2] = (short)f2bf(u2[2]); a1x[3] = (short)f2bf(u2[3]);
    }
    #pragma unroll
    for (int nt = 0; nt < 8; ++nt) {
      bf16x8 bv0 = ldf(wpk + PK_W1 + (nt * 2 + 0) * 512 + lo8);
      bf16x8 bv1 = ldf(wpk + PK_W1 + (nt * 2 + 1) * 512 + lo8);
      MFMA(a0,  bv0, acc[mi][nt]);
      MFMA(a1x, bv1, acc[mi][nt]);
    }
  }
  #pragma unroll
  for (int mi = 0; mi < 2; ++mi) {
    const int mt = 2 * w + mi;
    #pragma unroll
    for (int nt = 0; nt < 8; ++nt)
      #pragma unroll
      for (int e = 0; e < 4; ++e) {
        float v = fast_tanh(acc[mi][nt][e] + b1r[nt]);
        sA[(mt * 16 + q * 4 + e) * 136 + nt * 16 + c] = f2bf(v);
      }
  }
  __syncthreads();

  floatx4 acc2[2][2];
  #pragma unroll
  for (int mi = 0; mi < 2; ++mi)
    #pragma unroll
    for (int nt = 0; nt < 2; ++nt) acc2[mi][nt] = (floatx4){0.f, 0.f, 0.f, 0.f};

  #pragma unroll
  for (int kb = 0; kb < 4; ++kb) {
    bf16x8 av0 = ldf(&sA[((2 * w + 0) * 16 + c) * 136 + kb * 32 + q * 8]);
    bf16x8 av1 = ldf(&sA[((2 * w + 1) * 16 + c) * 136 + kb * 32 + q * 8]);
    #pragma unroll
    for (int nt = 0; nt < 2; ++nt) {
      bf16x8 bv = ldf(wpk + PK_W2 + (nt * 4 + kb) * 512 + lo8);
      MFMA(av0, bv, acc2[0][nt]);
      MFMA(av1, bv, acc2[1][nt]);
    }
  }
  #pragma unroll
  for (int mi = 0; mi < 2; ++mi) {
    const int mt = 2 * w + mi;
    #pragma unroll
    for (int nt = 0; nt < 2; ++nt)
      #pragma unroll
      for (int e = 0; e < 4; ++e) {
        float v = fast_tanh(acc2[mi][nt][e] + b2r[nt]);
        int m = mt * 16 + q * 4 + e;
        x2out[(size_t)(r0 + m) * 32 + nt * 16 + c] = f2bf(v);
      }
  }
}

// ---------------------------------------------------------------------------
// Kernel 2 (R6): merged-interval fused GRU. 512 thr = 8 waves, wave owns
// J-tile J=tid>>6. Interval t: L1(t) then L0(t+1); ONE barrier per interval.
// Buffers: L0(t) writes hl0[t&1], reads hl0[(t+1)&1];
//          L1(t) reads hl0[t&1] + hl1[(t+1)&1], writes hl1[t&1].
// ---------------------------------------------------------------------------
__global__ __launch_bounds__(512, 2) void gru_mg(
    const uint16_t* __restrict__ wpk, const uint16_t* __restrict__ x2,
    const float* __restrict__ bih0, const float* __restrict__ bhh0,
    const float* __restrict__ bih1, const float* __restrict__ bhh1,
    float* __restrict__ hout) {
  __shared__ uint16_t hl0[2][32 * 136];
  __shared__ uint16_t hl1[2][32 * 136];
  const int seq0 = blockIdx.x * 32;
  const int tid = threadIdx.x;
  const int J = tid >> 6, l = tid & 63, q = l >> 4, c = l & 15;
  const int lo8 = l * 8;

  { uint32_t* z0 = (uint32_t*)hl0;
    for (int i = tid; i < 2 * 32 * 68; i += 512) z0[i] = 0u;
    uint32_t* z1 = (uint32_t*)hl1;
    for (int i = tid; i < 2 * 32 * 68; i += 512) z1[i] = 0u; }

  // ---- resident weight fragments for this wave's J-tile (39 frags) ----
  bf16x8 wi0[3], wh0[3][4], wi1[3][4], wh1[3][4];
  #pragma unroll
  for (int g = 0; g < 3; ++g) {
    wi0[g] = ldf(wpk + PK_WIH0 + (g * 8 + J) * 512 + lo8);
    #pragma unroll
    for (int kb = 0; kb < 4; ++kb) {
      wh0[g][kb] = ldf(wpk + PK_WHH0 + ((g * 8 + J) * 4 + kb) * 512 + lo8);
      wi1[g][kb] = ldf(wpk + PK_WIH1 + ((g * 8 + J) * 4 + kb) * 512 + lo8);
      wh1[g][kb] = ldf(wpk + PK_WHH1 + ((g * 8 + J) * 4 + kb) * 512 + lo8);
    }
  }
  const int col = J * 16 + c;
  const float bR0 = bih0[col]       + bhh0[col];
  const float bZ0 = bih0[128 + col] + bhh0[128 + col];
  const float bN0 = bih0[256 + col];
  const float bH0 = bhh0[256 + col];
  const float bR1 = bih1[col]       + bhh1[col];
  const float bZ1 = bih1[128 + col] + bhh1[128 + col];
  const float bN1 = bih1[256 + col];
  const float bH1 = bhh1[256 + col];

  floatx4 h0m[2], h1m[2];
  h0m[0] = (floatx4){0.f, 0.f, 0.f, 0.f}; h0m[1] = (floatx4){0.f, 0.f, 0.f, 0.f};
  h1m[0] = (floatx4){0.f, 0.f, 0.f, 0.f}; h1m[1] = (floatx4){0.f, 0.f, 0.f, 0.f};

  __syncthreads();   // zeros visible before preamble writes

  // ---- preamble: L0(0). h0(-1)=0 so only x-part + biases. writes hl0[0]. ----
  {
    bf16x8 ax0 = ldf(x2 + (size_t)(seq0 + c) * 32 + q * 8);
    bf16x8 ax1 = ldf(x2 + (size_t)(seq0 + 16 + c) * 32 + q * 8);
    floatx4 aR[2], aZ[2], aN[2];
    #pragma unroll
    for (int mi = 0; mi < 2; ++mi) {
      aR[mi] = (floatx4){bR0, bR0, bR0, bR0};
      aZ[mi] = (floatx4){bZ0, bZ0, bZ0, bZ0};
      aN[mi] = (floatx4){bN0, bN0, bN0, bN0};
    }
    MFMA(ax0, wi0[0], aR[0]); MFMA(ax1, wi0[0], aR[1]);
    MFMA(ax0, wi0[1], aZ[0]); MFMA(ax1, wi0[1], aZ[1]);
    MFMA(ax0, wi0[2], aN[0]); MFMA(ax1, wi0[2], aN[1]);
    #pragma unroll
    for (int mi = 0; mi < 2; ++mi)
      #pragma unroll
      for (int e = 0; e < 4; ++e) {
        float r  = fast_sigmoid(aR[mi][e]);
        float zz = fast_sigmoid(aZ[mi][e]);
        float nn = fast_tanh(aN[mi][e] + r * bH0);
        float hv = nn - zz * nn;            // h0(-1)=0
        h0m[mi][e] = hv;
        hl0[0][(mi * 16 + q * 4 + e) * 136 + J * 16 + c] = f2bf(hv);
      }
  }
  __syncthreads();

  #pragma unroll 1
  for (int t = 0; t < TSTEPS; ++t) {
    const int cur = t & 1, nxt = cur ^ 1;
    const uint16_t* hA = hl0[cur];   // h0(t)
    const uint16_t* hB = hl1[nxt];   // h1(t-1)
    uint16_t* w1p = hl1[cur];        // h1(t)
    uint16_t* w0p = hl0[nxt];        // h0(t+1)
    const int tx = (t < TSTEPS - 1) ? t + 1 : t;
    bf16x8 ax0 = ldf(x2 + ((size_t)tx * NSEQ + seq0 + c) * 32 + q * 8);
    bf16x8 ax1 = ldf(x2 + ((size_t)tx * NSEQ + seq0 + 16 + c) * 32 + q * 8);

    // ---------------- L1(t) ----------------
    {
      floatx4 aR[2], aZ[2], aN[2], aH[2];
      #pragma unroll
      for (int mi = 0; mi < 2; ++mi) {
        aR[mi] = (floatx4){bR1, bR1, bR1, bR1};
        aZ[mi] = (floatx4){bZ1, bZ1, bZ1, bZ1};
        aN[mi] = (floatx4){bN1, bN1, bN1, bN1};
        aH[mi] = (floatx4){bH1, bH1, bH1, bH1};
      }
      #pragma unroll
      for (int kb = 0; kb < 4; ++kb) {
        bf16x8 a0 = ldf(hA + (c)      * 136 + kb * 32 + q * 8);
        bf16x8 a1 = ldf(hA + (16 + c) * 136 + kb * 32 + q * 8);
        bf16x8 b0 = ldf(hB + (c)      * 136 + kb * 32 + q * 8);
        bf16x8 b1 = ldf(hB + (16 + c) * 136 + kb * 32 + q * 8);
        MFMA(a0, wi1[0][kb], aR[0]); MFMA(a1, wi1[0][kb], aR[1]);
        MFMA(a0, wi1[1][kb], aZ[0]); MFMA(a1, wi1[1][kb], aZ[1]);
        MFMA(a0, wi1[2][kb], aN[0]); MFMA(a1, wi1[2][kb], aN[1]);
        MFMA(b0, wh1[0][kb], aR[0]); MFMA(b1, wh1[0][kb], aR[1]);
        MFMA(b0, wh1[1][kb], aZ[0]); MFMA(b1, wh1[1][kb], aZ[1]);
        MFMA(b0, wh1[2][kb], aH[0]); MFMA(b1, wh1[2][kb], aH[1]);
      }
      #pragma unroll
      for (int mi = 0; mi < 2; ++mi)
        #pragma unroll
        for (int e = 0; e < 4; ++e) {
          float r  = fast_sigmoid(aR[mi][e]);
          float zz = fast_sigmoid(aZ[mi][e]);
          float nn = fast_tanh(aN[mi][e] + r * aH[mi][e]);
          float hv = nn + zz * (h1m[mi][e] - nn);
          h1m[mi][e] = hv;
          w1p[(mi * 16 + q * 4 + e) * 136 + J * 16 + c] = f2bf(hv);
        }
    }

    // ---------------- L0(t+1) ----------------
    if (t < TSTEPS - 1) {
      floatx4 aR[2], aZ[2], aN[2], aH[2];
      #pragma unroll
      for (int mi = 0; mi < 2; ++mi) {
        aR[mi] = (floatx4){bR0, bR0, bR0, bR0};
        aZ[mi] = (floatx4){bZ0, bZ0, bZ0, bZ0};
        aN[mi] = (floatx4){bN0, bN0, bN0, bN0};
        aH[mi] = (floatx4){bH0, bH0, bH0, bH0};
      }
      #pragma unroll
      for (int kb = 0; kb < 4; ++kb) {
        bf16x8 a0 = ldf(hA + (c)      * 136 + kb * 32 + q * 8);
        bf16x8 a1 = ldf(hA + (16 + c) * 136 + kb * 32 + q * 8);
        MFMA(a0, wh0[0][kb], aR[0]); MFMA(a1, wh0[0][kb], aR[1]);
        MFMA(a0, wh0[1][kb], aZ[0]); MFMA(a1, wh0[1][kb], aZ[1]);
        MFMA(a0, wh0[2][kb], aH[0]); MFMA(a1, wh0[2][kb], aH[1]);
      }
      MFMA(ax0, wi0[0], aR[0]); MFMA(ax1, wi0[0], aR[1]);
      MFMA(ax0, wi0[1], aZ[0]); MFMA(ax1, wi0[1], aZ[1]);
      MFMA(ax0, wi0[2], aN[0]); MFMA(ax1, wi0[2], aN[1]);
      #pragma unroll
      for (int mi = 0; mi < 2; ++mi)
        #pragma unroll
        for (int e = 0; e < 4; ++e) {
          float r  = fast_sigmoid(aR[mi][e]);
          float zz = fast_sigmoid(aZ[mi][e]);
          float nn = fast_tanh(aN[mi][e] + r * aH[mi][e]);
          float hv = nn + zz * (h0m[mi][e] - nn);
          h0m[mi][e] = hv;
          w0p[(mi * 16 + q * 4 + e) * 136 + J * 16 + c] = f2bf(hv);
        }
    }
    __syncthreads();
  }

  #pragma unroll
  for (int mi = 0; mi < 2; ++mi)
    #pragma unroll
    for (int e = 0; e < 4; ++e) {
      int seq = seq0 + mi * 16 + q * 4 + e;
      hout[(size_t)seq * 128 + J * 16 + c] = h1m[mi][e];
    }
}

// ---------------------------------------------------------------------------
// Kernel 3: mean over routes + candidate head + fc1/fc2/fc3 (unchanged)
// ---------------------------------------------------------------------------
__global__ __launch_bounds__(192) void final_kernel(
    const float* __restrict__ hout, const float* __restrict__ cands,
    const float* __restrict__ cw, const float* __restrict__ cb,
    const float* __restrict__ f1w, const float* __restrict__ f1b,
    const float* __restrict__ f2w, const float* __restrict__ f2b,
    const float* __restrict__ f3w, const float* __restrict__ f3b,
    float* __restrict__ out) {
  __shared__ float hc[192];
  __shared__ float v1[128];
  __shared__ float v2[128];
  __shared__ float red[128];
  const int b = blockIdx.x, tid = threadIdx.x;
  if (tid < 128) {
    float s = 0.f;
    const float* hp = hout + (size_t)(b * 48) * 128 + tid;
    #pragma unroll 4
    for (int r = 0; r < 48; ++r) s += hp[r * 128];
    hc[tid] = s * (1.0f / 48.0f);
  } else {
    int j = tid - 128;
    float s = cb[j];
    const float* cp = cands + b * 72;
    #pragma unroll 8
    for (int k = 0; k < 72; ++k) s += cp[k] * cw[k * 64 + j];
    hc[128 + j] = s;
  }
  __syncthreads();
  if (tid < 128) {
    float s = f1b[tid];
    for (int k = 0; k < 192; ++k) s += hc[k] * f1w[k * 128 + tid];
    v1[tid] = fast_tanh(s);
  }
  __syncthreads();
  if (tid < 128) {
    float s = f2b[tid];
    for (int k = 0; k < 128; ++k) s += v1[k] * f2w[k * 128 + tid];
    v2[tid] = fast_tanh(s);
  }
  __syncthreads();
  if (tid < 128) red[tid] = v2[tid] * f3w[tid];
  __syncthreads();
  if (tid < 64) {
    float s = red[tid] + red[tid + 64];
    s += __shfl_down(s, 32);
    s += __shfl_down(s, 16);
    s += __shfl_down(s, 8);
    s += __shfl_down(s, 4);
    s += __shfl_down(s, 2);
    s += __shfl_down(s, 1);
    if (tid == 0) out[b] = s + f3b[0];
  }
}

// ---------------------------------------------------------------------------
extern "C" void kernel_launch(void* const* d_in, const int* in_sizes, int n_in,
                              void* d_out, int out_size, void* d_ws, size_t ws_size,
                              hipStream_t stream) {
  const float* cand  = (const float*)d_in[0];
  const float* cust  = (const float*)d_in[1];
  const float* w1    = (const float*)d_in[2];
  const float* b1    = (const float*)d_in[3];
  const float* w2    = (const float*)d_in[4];
  const float* b2    = (const float*)d_in[5];
  const float* wih0  = (const float*)d_in[6];
  const float* whh0  = (const float*)d_in[7];
  const float* bih0  = (const float*)d_in[8];
  const float* bhh0  = (const float*)d_in[9];
  const float* wih1  = (const float*)d_in[10];
  const float* whh1  = (const float*)d_in[11];
  const float* bih1  = (const float*)d_in[12];
  const float* bhh1  = (const float*)d_in[13];
  const float* cw    = (const float*)d_in[14];
  const float* cb    = (const float*)d_in[15];
  const float* f1w   = (const float*)d_in[16];
  const float* f1b   = (const float*)d_in[17];
  const float* f2w   = (const float*)d_in[18];
  const float* f2b   = (const float*)d_in[19];
  const float* f3w   = (const float*)d_in[20];
  const float* f3b   = (const float*)d_in[21];

  uint16_t* wsp = (uint16_t*)d_ws;
  uint16_t* x2p = wsp + X2_EL;
  float* hout = (float*)((char*)d_ws + HOUT_BYTE);
  float* outp = (float*)d_out;

  pack_weights<<<(PK_END + 255) / 256, 256, 0, stream>>>(w1, w2, wih0, whh0, wih1, whh1, wsp);
  mlp_kernel<<<(NSEQ * TSTEPS) / 128, 256, 0, stream>>>(cust, b1, b2, wsp, x2p);
  gru_mg<<<NSEQ / 32, 512, 0, stream>>>(wsp, x2p, bih0, bhh0, bih1, bhh1, hout);
  final_kernel<<<512, 192, 0, stream>>>(hout, cand, cw, cb, f1w, f1b, f2w, f2b, f3w, f3b, outp);
}